// Round 1
// baseline (225.356 us; speedup 1.0000x reference)
//
#include <hip/hip_runtime.h>

#define CROP 7
#define NBOX_B 2
#define NBOX_N 512
#define NCH 256

__global__ __launch_bounds__(256) void roialign_kernel(
    const float* __restrict__ f2, const float* __restrict__ f3,
    const float* __restrict__ f4, const float* __restrict__ f5,
    const float* __restrict__ f6, const float* __restrict__ boxes,
    float* __restrict__ out)
{
    const int box = blockIdx.x;            // 0 .. B*N-1
    const int b   = box / NBOX_N;

    // per-box scalar setup (redundant per thread; ~30 flops)
    const float y1b = boxes[box * 4 + 0];
    const float x1b = boxes[box * 4 + 1];
    const float y2b = boxes[box * 4 + 2];
    const float x2b = boxes[box * 4 + 3];
    const float bh = y2b - y1b;
    const float bw = x2b - x1b;
    const float areas_sqrt = sqrtf(bh * bw);

    // levels = clip(int(floor(log(a/224)/log(2)) + 4), 2, 6)
    float lvf = floorf(logf(areas_sqrt / 224.0f) / logf(2.0f)) + 4.0f;
    int lvl = (int)lvf;
    lvl = lvl < 2 ? 2 : (lvl > 6 ? 6 : lvl);

    const float scale = (float)(1 << lvl);   // exp2(lvl), exact
    const float by  = y1b / scale;
    const float bx  = x1b / scale;
    const float bhl = bh  / scale;
    const float bwl = bw  / scale;

    const int li = lvl - 2;                  // 0..4
    const float* feat;
    int W;
    switch (li) {
        case 0: feat = f2; W = 256; break;
        case 1: feat = f3; W = 128; break;
        case 2: feat = f4; W =  64; break;
        case 3: feat = f5; W =  32; break;
        default: feat = f6; W =  16; break;
    }
    const float bound = (float)(W - 1);
    feat += (size_t)b * W * W * NCH;

    const int cg = (threadIdx.x & 63) * 4;   // channel offset (float4 granule)
    const int pg = threadIdx.x >> 6;         // position group 0..3

    float* out_box = out + (size_t)box * (CROP * CROP * NCH);

    for (int pos = pg; pos < CROP * CROP; pos += 4) {
        const int i = pos / CROP;
        const int j = pos % CROP;

        const float gy = by + ((float)i + 0.5f) * bhl / 7.0f;
        const float gx = bx + ((float)j + 0.5f) * bwl / 7.0f;

        const float y0 = fminf(fmaxf(floorf(gy), 0.0f), bound);
        const float x0 = fminf(fmaxf(floorf(gx), 0.0f), bound);
        const float y1 = fminf(y0 + 1.0f, bound);
        const float x1 = fminf(x0 + 1.0f, bound);

        const float ly = gy - y0;
        const float lx = gx - x0;
        const float w00 = (1.0f - ly) * (1.0f - lx);
        const float w01 = (1.0f - ly) * lx;
        const float w10 = ly * (1.0f - lx);
        const float w11 = ly * lx;

        const int iy0 = (int)y0, iy1 = (int)y1;
        const int ix0 = (int)x0, ix1 = (int)x1;

        const float4 v00 = *(const float4*)(feat + ((iy0 * W + ix0) * NCH + cg));
        const float4 v01 = *(const float4*)(feat + ((iy0 * W + ix1) * NCH + cg));
        const float4 v10 = *(const float4*)(feat + ((iy1 * W + ix0) * NCH + cg));
        const float4 v11 = *(const float4*)(feat + ((iy1 * W + ix1) * NCH + cg));

        float4 o;
        o.x = w00 * v00.x + w01 * v01.x + w10 * v10.x + w11 * v11.x;
        o.y = w00 * v00.y + w01 * v01.y + w10 * v10.y + w11 * v11.y;
        o.z = w00 * v00.z + w01 * v01.z + w10 * v10.z + w11 * v11.z;
        o.w = w00 * v00.w + w01 * v01.w + w10 * v10.w + w11 * v11.w;

        *(float4*)(out_box + pos * NCH + cg) = o;
    }
}

extern "C" void kernel_launch(void* const* d_in, const int* in_sizes, int n_in,
                              void* d_out, int out_size, void* d_ws, size_t ws_size,
                              hipStream_t stream) {
    const float* f2    = (const float*)d_in[0];
    const float* f3    = (const float*)d_in[1];
    const float* f4    = (const float*)d_in[2];
    const float* f5    = (const float*)d_in[3];
    const float* f6    = (const float*)d_in[4];
    const float* boxes = (const float*)d_in[5];
    float* out = (float*)d_out;

    roialign_kernel<<<NBOX_B * NBOX_N, 256, 0, stream>>>(f2, f3, f4, f5, f6, boxes, out);
}

// Round 2
// 222.487 us; speedup vs baseline: 1.0129x; 1.0129x over previous
//
#include <hip/hip_runtime.h>

#define CROP 7
#define NBOX_B 2
#define NBOX_N 512
#define NCH 256

// one thread per (box, pos, 4-channel group):
//   total = B*N * 49 * 64 = 3,211,264 threads = 12544 blocks of 256
// wave (64 lanes) = all 64 channel-groups of one (box,pos): box/pos math is
// wave-uniform, loads are coalesced 1KB segments.
__global__ __launch_bounds__(256) void roialign_kernel(
    const float* __restrict__ f2, const float* __restrict__ f3,
    const float* __restrict__ f4, const float* __restrict__ f5,
    const float* __restrict__ f6, const float* __restrict__ boxes,
    float* __restrict__ out)
{
    const int gid = blockIdx.x * 256 + threadIdx.x;

    const int box = gid / (CROP * CROP * 64);            // 0 .. B*N-1
    const int rem = gid - box * (CROP * CROP * 64);
    const int pos = rem >> 6;                            // 0 .. 48
    const int cg  = (rem & 63) * 4;                      // channel offset
    const int b   = box / NBOX_N;

    const int i = pos / CROP;
    const int j = pos - i * CROP;

    // per-box scalar setup (wave-uniform)
    const float y1b = boxes[box * 4 + 0];
    const float x1b = boxes[box * 4 + 1];
    const float y2b = boxes[box * 4 + 2];
    const float x2b = boxes[box * 4 + 3];
    const float bh = y2b - y1b;
    const float bw = x2b - x1b;
    const float areas_sqrt = sqrtf(bh * bw);

    // levels = clip(int(floor(log(a/224)/log(2)) + 4), 2, 6)
    float lvf = floorf(logf(areas_sqrt / 224.0f) / logf(2.0f)) + 4.0f;
    int lvl = (int)lvf;
    lvl = lvl < 2 ? 2 : (lvl > 6 ? 6 : lvl);

    const float scale = (float)(1 << lvl);   // exp2(lvl), exact
    const float by  = y1b / scale;
    const float bx  = x1b / scale;
    const float bhl = bh  / scale;
    const float bwl = bw  / scale;

    const int li = lvl - 2;                  // 0..4
    const float* feat;
    int W;
    switch (li) {
        case 0: feat = f2; W = 256; break;
        case 1: feat = f3; W = 128; break;
        case 2: feat = f4; W =  64; break;
        case 3: feat = f5; W =  32; break;
        default: feat = f6; W =  16; break;
    }
    const float bound = (float)(W - 1);
    feat += (size_t)b * W * W * NCH;

    const float gy = by + ((float)i + 0.5f) * bhl / 7.0f;
    const float gx = bx + ((float)j + 0.5f) * bwl / 7.0f;

    const float y0 = fminf(fmaxf(floorf(gy), 0.0f), bound);
    const float x0 = fminf(fmaxf(floorf(gx), 0.0f), bound);
    const float y1 = fminf(y0 + 1.0f, bound);
    const float x1 = fminf(x0 + 1.0f, bound);

    const float ly = gy - y0;
    const float lx = gx - x0;
    const float w00 = (1.0f - ly) * (1.0f - lx);
    const float w01 = (1.0f - ly) * lx;
    const float w10 = ly * (1.0f - lx);
    const float w11 = ly * lx;

    const int iy0 = (int)y0, iy1 = (int)y1;
    const int ix0 = (int)x0, ix1 = (int)x1;

    const float4 v00 = *(const float4*)(feat + ((iy0 * W + ix0) * NCH + cg));
    const float4 v01 = *(const float4*)(feat + ((iy0 * W + ix1) * NCH + cg));
    const float4 v10 = *(const float4*)(feat + ((iy1 * W + ix0) * NCH + cg));
    const float4 v11 = *(const float4*)(feat + ((iy1 * W + ix1) * NCH + cg));

    float4 o;
    o.x = w00 * v00.x + w01 * v01.x + w10 * v10.x + w11 * v11.x;
    o.y = w00 * v00.y + w01 * v01.y + w10 * v10.y + w11 * v11.y;
    o.z = w00 * v00.z + w01 * v01.z + w10 * v10.z + w11 * v11.z;
    o.w = w00 * v00.w + w01 * v01.w + w10 * v10.w + w11 * v11.w;

    *(float4*)(out + (size_t)box * (CROP * CROP * NCH) + pos * NCH + cg) = o;
}

extern "C" void kernel_launch(void* const* d_in, const int* in_sizes, int n_in,
                              void* d_out, int out_size, void* d_ws, size_t ws_size,
                              hipStream_t stream) {
    const float* f2    = (const float*)d_in[0];
    const float* f3    = (const float*)d_in[1];
    const float* f4    = (const float*)d_in[2];
    const float* f5    = (const float*)d_in[3];
    const float* f6    = (const float*)d_in[4];
    const float* boxes = (const float*)d_in[5];
    float* out = (float*)d_out;

    const int total  = NBOX_B * NBOX_N * CROP * CROP * 64;  // 3,211,264
    const int blocks = total / 256;                          // 12544
    roialign_kernel<<<blocks, 256, 0, stream>>>(f2, f3, f4, f5, f6, boxes, out);
}

// Round 3
// 219.659 us; speedup vs baseline: 1.0259x; 1.0129x over previous
//
#include <hip/hip_runtime.h>

#define CROP 7
#define NBOX_B 2
#define NBOX_N 512
#define NCH 256
#define NPAIR 25   // ceil(49/2) position-pairs per box

typedef float v4f __attribute__((ext_vector_type(4)));

// one thread per (box, position-pair, 4-channel group):
//   total = 1024 boxes * 25 pairs * 64 cgroups = 1,638,400 threads = 6400 blocks
// wave (64 lanes) = all 64 channel-groups of one (box, pos-pair): box/pos math
// wave-uniform, loads coalesced 1KB segments, 8 loads in flight per thread.
__global__ __launch_bounds__(256) void roialign_kernel(
    const float* __restrict__ f2, const float* __restrict__ f3,
    const float* __restrict__ f4, const float* __restrict__ f5,
    const float* __restrict__ f6, const float* __restrict__ boxes,
    float* __restrict__ out)
{
    const int gid = blockIdx.x * 256 + threadIdx.x;

    const int box = gid / (NPAIR * 64);
    const int rem = gid - box * (NPAIR * 64);
    const int pp  = rem >> 6;                 // 0..24
    const int cg  = (rem & 63) * 4;           // channel offset
    const int b   = box / NBOX_N;

    // ---- per-box setup (wave-uniform; identical math to passing version) ----
    const float y1b = boxes[box * 4 + 0];
    const float x1b = boxes[box * 4 + 1];
    const float y2b = boxes[box * 4 + 2];
    const float x2b = boxes[box * 4 + 3];
    const float bh = y2b - y1b;
    const float bw = x2b - x1b;
    const float areas_sqrt = sqrtf(bh * bw);

    float lvf = floorf(logf(areas_sqrt / 224.0f) / logf(2.0f)) + 4.0f;
    int lvl = (int)lvf;
    lvl = lvl < 2 ? 2 : (lvl > 6 ? 6 : lvl);

    const float scale = (float)(1 << lvl);
    const float by  = y1b / scale;
    const float bx  = x1b / scale;
    const float bhl = bh  / scale;
    const float bwl = bw  / scale;

    const int li = lvl - 2;
    const float* feat;
    int W;
    switch (li) {
        case 0: feat = f2; W = 256; break;
        case 1: feat = f3; W = 128; break;
        case 2: feat = f4; W =  64; break;
        case 3: feat = f5; W =  32; break;
        default: feat = f6; W =  16; break;
    }
    const float bound = (float)(W - 1);
    feat += (size_t)b * W * W * NCH;

    // ---- two positions per thread ----
    const int pos0 = pp * 2;
    const int pos1 = pos0 + 1;
    const bool has1 = (pos1 < CROP * CROP);

    int i0 = pos0 / CROP, j0 = pos0 - i0 * CROP;
    int i1p = has1 ? pos1 : pos0;
    int i1 = i1p / CROP, j1 = i1p - i1 * CROP;

    // tap math for both positions
    float w00a, w01a, w10a, w11a, w00b, w01b, w10b, w11b;
    int off00a, off01a, off10a, off11a, off00b, off01b, off10b, off11b;
    {
        const float gy = by + ((float)i0 + 0.5f) * bhl / 7.0f;
        const float gx = bx + ((float)j0 + 0.5f) * bwl / 7.0f;
        const float y0 = fminf(fmaxf(floorf(gy), 0.0f), bound);
        const float x0 = fminf(fmaxf(floorf(gx), 0.0f), bound);
        const float y1 = fminf(y0 + 1.0f, bound);
        const float x1 = fminf(x0 + 1.0f, bound);
        const float ly = gy - y0, lx = gx - x0;
        w00a = (1.0f - ly) * (1.0f - lx);
        w01a = (1.0f - ly) * lx;
        w10a = ly * (1.0f - lx);
        w11a = ly * lx;
        const int iy0 = (int)y0, iy1 = (int)y1, ix0 = (int)x0, ix1 = (int)x1;
        off00a = (iy0 * W + ix0) * NCH + cg;
        off01a = (iy0 * W + ix1) * NCH + cg;
        off10a = (iy1 * W + ix0) * NCH + cg;
        off11a = (iy1 * W + ix1) * NCH + cg;
    }
    {
        const float gy = by + ((float)i1 + 0.5f) * bhl / 7.0f;
        const float gx = bx + ((float)j1 + 0.5f) * bwl / 7.0f;
        const float y0 = fminf(fmaxf(floorf(gy), 0.0f), bound);
        const float x0 = fminf(fmaxf(floorf(gx), 0.0f), bound);
        const float y1 = fminf(y0 + 1.0f, bound);
        const float x1 = fminf(x0 + 1.0f, bound);
        const float ly = gy - y0, lx = gx - x0;
        w00b = (1.0f - ly) * (1.0f - lx);
        w01b = (1.0f - ly) * lx;
        w10b = ly * (1.0f - lx);
        w11b = ly * lx;
        const int iy0 = (int)y0, iy1 = (int)y1, ix0 = (int)x0, ix1 = (int)x1;
        off00b = (iy0 * W + ix0) * NCH + cg;
        off01b = (iy0 * W + ix1) * NCH + cg;
        off10b = (iy1 * W + ix0) * NCH + cg;
        off11b = (iy1 * W + ix1) * NCH + cg;
    }

    // issue all 8 loads before any use
    const v4f v00a = *(const v4f*)(feat + off00a);
    const v4f v01a = *(const v4f*)(feat + off01a);
    const v4f v10a = *(const v4f*)(feat + off10a);
    const v4f v11a = *(const v4f*)(feat + off11a);
    const v4f v00b = *(const v4f*)(feat + off00b);
    const v4f v01b = *(const v4f*)(feat + off01b);
    const v4f v10b = *(const v4f*)(feat + off10b);
    const v4f v11b = *(const v4f*)(feat + off11b);

    v4f oa = w00a * v00a + w01a * v01a + w10a * v10a + w11a * v11a;
    v4f ob = w00b * v00b + w01b * v01b + w10b * v10b + w11b * v11b;

    float* out_box = out + (size_t)box * (CROP * CROP * NCH);
    __builtin_nontemporal_store(oa, (v4f*)(out_box + pos0 * NCH + cg));
    if (has1) {
        __builtin_nontemporal_store(ob, (v4f*)(out_box + pos1 * NCH + cg));
    }
}

extern "C" void kernel_launch(void* const* d_in, const int* in_sizes, int n_in,
                              void* d_out, int out_size, void* d_ws, size_t ws_size,
                              hipStream_t stream) {
    const float* f2    = (const float*)d_in[0];
    const float* f3    = (const float*)d_in[1];
    const float* f4    = (const float*)d_in[2];
    const float* f5    = (const float*)d_in[3];
    const float* f6    = (const float*)d_in[4];
    const float* boxes = (const float*)d_in[5];
    float* out = (float*)d_out;

    const int total  = NBOX_B * NBOX_N * NPAIR * 64;  // 1,638,400
    const int blocks = total / 256;                    // 6400
    roialign_kernel<<<blocks, 256, 0, stream>>>(f2, f3, f4, f5, f6, boxes, out);
}